// Round 8
// baseline (51.522 us; speedup 1.0000x reference)
//
#include <hip/hip_runtime.h>
#include <hip/hip_bf16.h>
#include <stdint.h>

// SimCLR loss, n=8192, d=128, T=0.07.
// R8 = R7 (LDS-staged B, the proven fix for the per-wave B-gather bottleneck)
// + SYMMETRY: sim is symmetric, so only triangle band-blocks are computed.
// 32 bands x 256; 528 blocks (vs 1024 full), each staging 2x128-col chunks.
// Off-diag blocks: tile exp values reduced over cols -> E[row band] AND over
// rows -> E[col band] (2 shuffles + atomic). Diag blocks: full square, row
// sums only. Every ordered pair (i,j) counted exactly once; j==i removed
// analytically in finalize. MFMA work halves: 1.05M -> 540K (floor 4.4us).
//  k_normalize: fp32 -> row-L2-normalized bf16 fn; block 0 zeroes E
//  k_simexp:    triangle tiles -> atomicAdd into E[8192]
//  k_finalize:  per-row term -> block partials; k_reduce: mean -> out[0]

#define N_ROWS 8192
#define DIM    128
#define HALF_N 4096
#define NBANDS 32
#define BROWS  256                       // band width (rows and cols)
#define NTRI   (NBANDS * (NBANDS + 1) / 2)   // 528 blocks
#define CHUNK  128                       // staged cols per chunk (32 KiB)
#define NCH    (BROWS / CHUNK)           // 2 chunks per block
#define NJT    (CHUNK / 16)              // 8 j-tiles per chunk

static constexpr float INV_T = 14.285714285714286f;   // 1/0.07
static constexpr float SCALE = 20.60992915555662f;    // log2(e)/0.07

typedef __attribute__((ext_vector_type(8))) short short8;   // 8 bf16 = 4 VGPR
typedef __attribute__((ext_vector_type(4))) float f32x4;

#if __has_builtin(__builtin_amdgcn_exp2f)
__device__ inline float fast_exp2(float x) { return __builtin_amdgcn_exp2f(x); }
#else
__device__ inline float fast_exp2(float x) { return exp2f(x); }
#endif

__device__ inline float bf_lo(uint32_t u) { return __uint_as_float(u << 16); }
__device__ inline float bf_hi(uint32_t u) { return __uint_as_float(u & 0xFFFF0000u); }
__device__ inline uint16_t f2bf(float x) {
    uint32_t u = __float_as_uint(x);
    return (uint16_t)((u + 0x7FFFu + ((u >> 16) & 1u)) >> 16);   // RNE
}

// async global->LDS, 16B/lane; LDS dest = wave-uniform base + lane*16 (HW)
__device__ inline void load_lds16(const void* g, void* l) {
    __builtin_amdgcn_global_load_lds(
        (const __attribute__((address_space(1))) uint32_t*)g,
        (__attribute__((address_space(3))) uint32_t*)l, 16, 0, 0);
}

// ---------------- kernel 1: row L2-normalize, fp32 -> bf16; zero E --------
__global__ __launch_bounds__(256) void k_normalize(const float* __restrict__ f,
                                                   uint16_t* __restrict__ fn,
                                                   float* __restrict__ E) {
    if (blockIdx.x == 0) {               // zero E (runs before k_simexp)
        float4 z = {0.f, 0.f, 0.f, 0.f};
        #pragma unroll
        for (int i = 0; i < 8; ++i)
            ((float4*)E)[threadIdx.x + i * 256] = z;
    }
    int wid  = (blockIdx.x * blockDim.x + threadIdx.x) >> 6;   // one wave per row
    int lane = threadIdx.x & 63;
    const float2* src = (const float2*)(f + (size_t)wid * DIM);
    float2 v = src[lane];
    float ss = v.x * v.x + v.y * v.y;
    #pragma unroll
    for (int m = 1; m < 64; m <<= 1) ss += __shfl_xor(ss, m, 64);
    float inv = rsqrtf(ss);
    ushort2 o;
    o.x = f2bf(v.x * inv);
    o.y = f2bf(v.y * inv);
    ((ushort2*)(fn + (size_t)wid * DIM))[lane] = o;
}

// ---------------- kernel 2: triangle sim + exp-sum (MFMA, LDS-staged) -----
// LDS chunk layout: col cc (0..127) at bytes cc*256; 16B slot pc holds
// logical k-chunk pc ^ (cc&7)  (validated swizzle from R7).
__global__ __launch_bounds__(256) void k_simexp(const uint16_t* __restrict__ fn,
                                                float* __restrict__ E) {
    __shared__ __align__(16) uint16_t Bl[2][CHUNK * DIM];   // 2 x 32 KiB
    // decode triangular block index (scalar loop, <=32 iters)
    int bx = 0, rem = blockIdx.x;
    while (rem >= NBANDS - bx) { rem -= NBANDS - bx; ++bx; }
    const int by = bx + rem;
    const bool diag = (by == bx);

    const int tid  = threadIdx.x;
    const int lane = tid & 63;
    const int w    = tid >> 6;
    const int ib   = bx * BROWS + w * 64;
    const int jb   = by * BROWS;
    const int lr = lane & 15;
    const int lk = lane >> 4;

    const short8* fn8 = (const short8*)fn;

    // A fragments: row ib+mt*16+lr, dims kc*32+lk*8..+8  (64 VGPR)
    short8 Af[4][4];
    #pragma unroll
    for (int mt = 0; mt < 4; ++mt)
        #pragma unroll
        for (int kc = 0; kc < 4; ++kc)
            Af[mt][kc] = fn8[(size_t)(ib + mt * 16 + lr) * 16 + kc * 4 + lk];

    float es[4][4];
    #pragma unroll
    for (int mt = 0; mt < 4; ++mt)
        #pragma unroll
        for (int r = 0; r < 4; ++r) es[mt][r] = 0.0f;

    // staging: wave w covers chunk cols w*32..+31; 8 instrs x 64 lanes x 16B
    const int scc0 = w * 32 + (lane >> 4);
    #define STAGE(c, buf)                                                     \
        _Pragma("unroll")                                                     \
        for (int i = 0; i < 8; ++i) {                                         \
            int cc = scc0 + i * 4;                                            \
            int lc = (lane & 15) ^ (cc & 7);                                  \
            load_lds16(fn8 + (size_t)(jb + (c) * CHUNK + cc) * 16 + lc,       \
                       &Bl[buf][w * 4096 + i * 512]);                         \
        }

    STAGE(0, 0)

    for (int c = 0; c < NCH; ++c) {
        __syncthreads();                       // stage(c) drained & visible
        if (c + 1 < NCH) {
            STAGE(c + 1, (c + 1) & 1)          // DMA overlaps compute(c)
        }
        const char* bp = (const char*)&Bl[c & 1][0];
        #pragma unroll
        for (int jt = 0; jt < NJT; ++jt) {
            const int rbase = (jt * 16 + lr) * 256;
            short8 Bf[4];
            #pragma unroll
            for (int kc = 0; kc < 4; ++kc)
                Bf[kc] = *(const short8*)(bp + rbase + ((((kc << 2) | lk) ^ (lr & 7)) << 4));
            float cs = 0.0f;
            #pragma unroll
            for (int mt = 0; mt < 4; ++mt) {
                f32x4 acc = {0.0f, 0.0f, 0.0f, 0.0f};
                #pragma unroll
                for (int kc = 0; kc < 4; ++kc)
                    acc = __builtin_amdgcn_mfma_f32_16x16x32_bf16(Af[mt][kc], Bf[kc], acc, 0, 0, 0);
                #pragma unroll
                for (int r = 0; r < 4; ++r) {
                    float e = fast_exp2(fmaf(acc[r], SCALE, -SCALE));
                    es[mt][r] += e;           // row accumulator
                    cs += e;                  // col partial (this wave's rows)
                }
            }
            if (!diag) {
                // col j = jb + c*128 + jt*16 + lr; reduce over lk groups
                cs += __shfl_xor(cs, 16, 64);
                cs += __shfl_xor(cs, 32, 64);
                if (lk == 0)
                    atomicAdd(&E[jb + c * CHUNK + jt * 16 + lr], cs);
            }
        }
    }

    // row sums: D col = lr, row = lk*4 + r; reduce over 16 col-lanes.
    #pragma unroll
    for (int mt = 0; mt < 4; ++mt)
        #pragma unroll
        for (int r = 0; r < 4; ++r) {
            float v = es[mt][r];
            v += __shfl_xor(v, 1, 64);
            v += __shfl_xor(v, 2, 64);
            v += __shfl_xor(v, 4, 64);
            v += __shfl_xor(v, 8, 64);
            if (lr == 0)
                atomicAdd(&E[ib + mt * 16 + lk * 4 + r], v);
        }
}

// ---------------- kernel 3: per-row finalize -> block partials ------------
__global__ __launch_bounds__(256) void k_finalize(const uint16_t* __restrict__ fn,
                                                  const float* __restrict__ E,
                                                  float* __restrict__ terms) {
    __shared__ float sm[4];
    int wid  = (blockIdx.x * blockDim.x + threadIdx.x) >> 6;   // one wave per row
    int lane = threadIdx.x & 63;
    int partner = (wid + HALF_N) & (N_ROWS - 1);
    const uint32_t* fr = (const uint32_t*)(fn + (size_t)wid * DIM);
    const uint32_t* pr = (const uint32_t*)(fn + (size_t)partner * DIM);
    uint32_t a = fr[lane], p = pr[lane];
    float a0 = bf_lo(a), a1 = bf_hi(a);
    float p0 = bf_lo(p), p1 = bf_hi(p);
    float sd = a0 * a0 + a1 * a1;       // self dot (diagonal recompute)
    float pd = a0 * p0 + a1 * p1;       // positive-pair dot
    #pragma unroll
    for (int m = 1; m < 64; m <<= 1) {
        sd += __shfl_xor(sd, m, 64);
        pd += __shfl_xor(pd, m, 64);
    }
    if (lane == 0) {
        float ep = E[wid] - fast_exp2(fmaf(sd, SCALE, -SCALE));   // drop diag
        sm[threadIdx.x >> 6] = INV_T + logf(ep) - pd * INV_T;
    }
    __syncthreads();
    if (threadIdx.x == 0)
        terms[blockIdx.x] = sm[0] + sm[1] + sm[2] + sm[3];
}

// ---------------- kernel 4: mean over 2048 block partials ----------------
__global__ __launch_bounds__(256) void k_reduce(const float* __restrict__ terms,
                                                float* __restrict__ out) {
    __shared__ float sm[4];
    float acc = 0.0f;
    for (int i = threadIdx.x; i < N_ROWS / 4; i += 256) acc += terms[i];
    #pragma unroll
    for (int m = 1; m < 64; m <<= 1) acc += __shfl_xor(acc, m, 64);
    if ((threadIdx.x & 63) == 0) sm[threadIdx.x >> 6] = acc;
    __syncthreads();
    if (threadIdx.x == 0)
        out[0] = (sm[0] + sm[1] + sm[2] + sm[3]) * (1.0f / N_ROWS);
}

extern "C" void kernel_launch(void* const* d_in, const int* in_sizes, int n_in,
                              void* d_out, int out_size, void* d_ws, size_t ws_size,
                              hipStream_t stream) {
    const float* feat = (const float*)d_in[0];
    float* out = (float*)d_out;

    // ws: fn (bf16, 2 MiB) | E (f32, 32 KiB) | terms (f32, 8 KiB)
    uint16_t* fn = (uint16_t*)d_ws;
    float* E     = (float*)((char*)d_ws + (size_t)N_ROWS * DIM * 2);
    float* terms = E + N_ROWS;

    k_normalize<<<dim3(N_ROWS / 4), dim3(256), 0, stream>>>(feat, fn, E);
    k_simexp<<<dim3(NTRI), dim3(256), 0, stream>>>(fn, E);
    k_finalize<<<dim3(N_ROWS / 4), dim3(256), 0, stream>>>(fn, E, terms);
    k_reduce<<<dim3(1), dim3(256), 0, stream>>>(terms, out);
}

// Round 9
// 43.918 us; speedup vs baseline: 1.1732x; 1.1732x over previous
//
#include <hip/hip_runtime.h>
#include <hip/hip_bf16.h>
#include <stdint.h>

// SimCLR loss, n=8192, d=128, T=0.07.
// R9 = R7's LDS-staged structure + symmetry at FINE granularity.
// R8 lesson: 528 big blocks @2/CU -> 16-straggler tail ate the 2x symmetry
// win. Now 64 bands x 128 -> 2080 blocks of 128x128 (4 waves x 32 rows),
// 32 KB LDS (2 x 16KB chunks, double-buffered, validated XOR swizzle) ->
// ~5 blocks/CU, ~8 blocks sequential work per CU (tail ~6%).
// Off-diag blocks: tile exps reduce over cols -> E[row band] AND over rows
// -> E[col band]. Diag blocks: full square, row sums only. Every ordered
// pair counted once; j==i removed analytically in finalize.
//  k_normalize: fp32 -> row-L2-normalized bf16 fn; block 0 zeroes E
//  k_simexp:    triangle band blocks -> atomicAdd into E[8192]
//  k_finalize:  per-row term -> terms[];  k_reduce: mean -> out[0]

#define N_ROWS 8192
#define DIM    128
#define HALF_N 4096
#define NBANDS 64
#define BROWS  128                           // band width
#define NTRI   (NBANDS * (NBANDS + 1) / 2)   // 2080 blocks
#define CHUNK  64                            // staged cols per chunk (16 KiB)
#define NCH    (BROWS / CHUNK)               // 2 chunks per block
#define NJT    (CHUNK / 16)                  // 4 j-tiles per chunk

static constexpr float INV_T = 14.285714285714286f;   // 1/0.07
static constexpr float SCALE = 20.60992915555662f;    // log2(e)/0.07

typedef __attribute__((ext_vector_type(8))) short short8;   // 8 bf16 = 4 VGPR
typedef __attribute__((ext_vector_type(4))) float f32x4;

#if __has_builtin(__builtin_amdgcn_exp2f)
__device__ inline float fast_exp2(float x) { return __builtin_amdgcn_exp2f(x); }
#else
__device__ inline float fast_exp2(float x) { return exp2f(x); }
#endif

__device__ inline float bf_lo(uint32_t u) { return __uint_as_float(u << 16); }
__device__ inline float bf_hi(uint32_t u) { return __uint_as_float(u & 0xFFFF0000u); }
__device__ inline uint16_t f2bf(float x) {
    uint32_t u = __float_as_uint(x);
    return (uint16_t)((u + 0x7FFFu + ((u >> 16) & 1u)) >> 16);   // RNE
}

// async global->LDS, 16B/lane; LDS dest = wave-uniform base + lane*16 (HW)
__device__ inline void load_lds16(const void* g, void* l) {
    __builtin_amdgcn_global_load_lds(
        (const __attribute__((address_space(1))) uint32_t*)g,
        (__attribute__((address_space(3))) uint32_t*)l, 16, 0, 0);
}

// ---------------- kernel 1: row L2-normalize, fp32 -> bf16; zero E --------
__global__ __launch_bounds__(256) void k_normalize(const float* __restrict__ f,
                                                   uint16_t* __restrict__ fn,
                                                   float* __restrict__ E) {
    if (blockIdx.x == 0) {               // zero E (completes before k_simexp)
        float4 z = {0.f, 0.f, 0.f, 0.f};
        #pragma unroll
        for (int i = 0; i < 8; ++i)
            ((float4*)E)[threadIdx.x + i * 256] = z;
    }
    int wid  = (blockIdx.x * blockDim.x + threadIdx.x) >> 6;   // one wave per row
    int lane = threadIdx.x & 63;
    const float2* src = (const float2*)(f + (size_t)wid * DIM);
    float2 v = src[lane];
    float ss = v.x * v.x + v.y * v.y;
    #pragma unroll
    for (int m = 1; m < 64; m <<= 1) ss += __shfl_xor(ss, m, 64);
    float inv = rsqrtf(ss);
    ushort2 o;
    o.x = f2bf(v.x * inv);
    o.y = f2bf(v.y * inv);
    ((ushort2*)(fn + (size_t)wid * DIM))[lane] = o;
}

// ---------------- kernel 2: triangle sim + exp-sum (MFMA, LDS-staged) -----
// LDS chunk: col cc (0..63) at bytes cc*256; 16B slot pc holds logical
// k-chunk pc ^ (cc&7)  (bank-spread; validated in R7).
__global__ __launch_bounds__(256) void k_simexp(const uint16_t* __restrict__ fn,
                                                float* __restrict__ E) {
    __shared__ __align__(16) uint16_t Bl[2][CHUNK * DIM];   // 2 x 16 KiB
    // decode triangular block index (scalar loop, <=64 iters, SALU)
    int bx = 0, rem = blockIdx.x;
    while (rem >= NBANDS - bx) { rem -= NBANDS - bx; ++bx; }
    const int by = bx + rem;
    const bool diag = (by == bx);

    const int tid  = threadIdx.x;
    const int lane = tid & 63;
    const int w    = tid >> 6;
    const int ib   = bx * BROWS + w * 32;
    const int jb   = by * BROWS;
    const int lr = lane & 15;
    const int lk = lane >> 4;

    const short8* fn8 = (const short8*)fn;

    // A fragments: row ib+mt*16+lr, dims kc*32+lk*8..+8  (32 VGPR)
    short8 Af[2][4];
    #pragma unroll
    for (int mt = 0; mt < 2; ++mt)
        #pragma unroll
        for (int kc = 0; kc < 4; ++kc)
            Af[mt][kc] = fn8[(size_t)(ib + mt * 16 + lr) * 16 + kc * 4 + lk];

    float es[2][4];
    #pragma unroll
    for (int mt = 0; mt < 2; ++mt)
        #pragma unroll
        for (int r = 0; r < 4; ++r) es[mt][r] = 0.0f;

    // staging: wave w covers chunk cols w*16..+15; 4 instrs x 64 lanes x 16B
    const int scc0 = w * 16 + (lane >> 4);
    #define STAGE(c, buf)                                                     \
        _Pragma("unroll")                                                     \
        for (int i = 0; i < 4; ++i) {                                         \
            int cc = scc0 + i * 4;                                            \
            int lc = (lane & 15) ^ (cc & 7);                                  \
            load_lds16(fn8 + (size_t)(jb + (c) * CHUNK + cc) * 16 + lc,       \
                       &Bl[buf][w * 2048 + i * 512]);                         \
        }

    STAGE(0, 0)

    for (int c = 0; c < NCH; ++c) {
        __syncthreads();                       // stage(c) drained & visible
        if (c + 1 < NCH) {
            STAGE(c + 1, (c + 1) & 1)          // DMA overlaps compute(c)
        }
        const char* bp = (const char*)&Bl[c & 1][0];
        #pragma unroll
        for (int jt = 0; jt < NJT; ++jt) {
            const int rbase = (jt * 16 + lr) * 256;
            short8 Bf[4];
            #pragma unroll
            for (int kc = 0; kc < 4; ++kc)
                Bf[kc] = *(const short8*)(bp + rbase + ((((kc << 2) | lk) ^ (lr & 7)) << 4));
            float cs = 0.0f;
            #pragma unroll
            for (int mt = 0; mt < 2; ++mt) {
                f32x4 acc = {0.0f, 0.0f, 0.0f, 0.0f};
                #pragma unroll
                for (int kc = 0; kc < 4; ++kc)
                    acc = __builtin_amdgcn_mfma_f32_16x16x32_bf16(Af[mt][kc], Bf[kc], acc, 0, 0, 0);
                #pragma unroll
                for (int r = 0; r < 4; ++r) {
                    float e = fast_exp2(fmaf(acc[r], SCALE, -SCALE));
                    es[mt][r] += e;           // row accumulator
                    cs += e;                  // col partial (this wave's rows)
                }
            }
            if (!diag) {
                // col j = jb + c*64 + jt*16 + lr; reduce over lk groups
                cs += __shfl_xor(cs, 16, 64);
                cs += __shfl_xor(cs, 32, 64);
                if (lk == 0)
                    atomicAdd(&E[jb + c * CHUNK + jt * 16 + lr], cs);
            }
        }
    }

    // row sums: D col = lr, row = lk*4 + r; reduce over 16 col-lanes.
    #pragma unroll
    for (int mt = 0; mt < 2; ++mt)
        #pragma unroll
        for (int r = 0; r < 4; ++r) {
            float v = es[mt][r];
            v += __shfl_xor(v, 1, 64);
            v += __shfl_xor(v, 2, 64);
            v += __shfl_xor(v, 4, 64);
            v += __shfl_xor(v, 8, 64);
            if (lr == 0)
                atomicAdd(&E[ib + mt * 16 + lk * 4 + r], v);
        }
}

// ---------------- kernel 3: per-row finalize -> block partials ------------
__global__ __launch_bounds__(256) void k_finalize(const uint16_t* __restrict__ fn,
                                                  const float* __restrict__ E,
                                                  float* __restrict__ terms) {
    __shared__ float sm[4];
    int wid  = (blockIdx.x * blockDim.x + threadIdx.x) >> 6;   // one wave per row
    int lane = threadIdx.x & 63;
    int partner = (wid + HALF_N) & (N_ROWS - 1);
    const uint32_t* fr = (const uint32_t*)(fn + (size_t)wid * DIM);
    const uint32_t* pr = (const uint32_t*)(fn + (size_t)partner * DIM);
    uint32_t a = fr[lane], p = pr[lane];
    float a0 = bf_lo(a), a1 = bf_hi(a);
    float p0 = bf_lo(p), p1 = bf_hi(p);
    float sd = a0 * a0 + a1 * a1;       // self dot (diagonal recompute)
    float pd = a0 * p0 + a1 * p1;       // positive-pair dot
    #pragma unroll
    for (int m = 1; m < 64; m <<= 1) {
        sd += __shfl_xor(sd, m, 64);
        pd += __shfl_xor(pd, m, 64);
    }
    if (lane == 0) {
        float ep = E[wid] - fast_exp2(fmaf(sd, SCALE, -SCALE));   // drop diag
        sm[threadIdx.x >> 6] = INV_T + logf(ep) - pd * INV_T;
    }
    __syncthreads();
    if (threadIdx.x == 0)
        terms[blockIdx.x] = sm[0] + sm[1] + sm[2] + sm[3];
}

// ---------------- kernel 4: mean over 2048 block partials ----------------
__global__ __launch_bounds__(256) void k_reduce(const float* __restrict__ terms,
                                                float* __restrict__ out) {
    __shared__ float sm[4];
    float acc = 0.0f;
    for (int i = threadIdx.x; i < N_ROWS / 4; i += 256) acc += terms[i];
    #pragma unroll
    for (int m = 1; m < 64; m <<= 1) acc += __shfl_xor(acc, m, 64);
    if ((threadIdx.x & 63) == 0) sm[threadIdx.x >> 6] = acc;
    __syncthreads();
    if (threadIdx.x == 0)
        out[0] = (sm[0] + sm[1] + sm[2] + sm[3]) * (1.0f / N_ROWS);
}

extern "C" void kernel_launch(void* const* d_in, const int* in_sizes, int n_in,
                              void* d_out, int out_size, void* d_ws, size_t ws_size,
                              hipStream_t stream) {
    const float* feat = (const float*)d_in[0];
    float* out = (float*)d_out;

    // ws: fn (bf16, 2 MiB) | E (f32, 32 KiB) | terms (f32, 8 KiB)
    uint16_t* fn = (uint16_t*)d_ws;
    float* E     = (float*)((char*)d_ws + (size_t)N_ROWS * DIM * 2);
    float* terms = E + N_ROWS;

    k_normalize<<<dim3(N_ROWS / 4), dim3(256), 0, stream>>>(feat, fn, E);
    k_simexp<<<dim3(NTRI), dim3(256), 0, stream>>>(fn, E);
    k_finalize<<<dim3(N_ROWS / 4), dim3(256), 0, stream>>>(fn, E, terms);
    k_reduce<<<dim3(1), dim3(256), 0, stream>>>(terms, out);
}